// Round 2
// baseline (1147.120 us; speedup 1.0000x reference)
//
#include <hip/hip_runtime.h>
#include <hip/hip_bf16.h>

#define DEV __device__ __forceinline__

typedef __bf16 bf16;
typedef __attribute__((ext_vector_type(8))) __bf16 bf16x8;
typedef __attribute__((ext_vector_type(4))) __bf16 bf16x4;
typedef __attribute__((ext_vector_type(4))) float f32x4;

static constexpr int B = 16, S = 1024, D = 512, HD = 64, FF = 2048;
static constexpr int BS = B * S;          // 16384 rows
static constexpr int QKVLD = 192;         // fused q|k|v row stride

typedef const __attribute__((address_space(1))) void gas_void;
typedef __attribute__((address_space(3))) void las_void;

DEV void gload16(const void* g, void* l) {
  // async global->LDS, 16B per lane; LDS dest = wave-uniform base + lane*16
  __builtin_amdgcn_global_load_lds((gas_void*)g, (las_void*)l, 16, 0, 0);
}

DEV void store_out(float* p, float v) { *p = v; }
DEV void store_out(bf16* p, float v) { *p = (bf16)v; }

// ---------------------------------------------------------------------------
// Generic A * B^T MFMA GEMM. A: [M,K] row-major (lda), Bt: [N,K] row-major
// (ldb), C: [M,N] (ldc). All tile dims divide problem dims (no bounds checks).
// Waves: WM x WN, each wave owns (BM/WM)x(BN/WN), fragments 16x16x32 bf16.
// ---------------------------------------------------------------------------
template<int BM, int BN, int BK, int WM, int WN, typename OutT>
__global__ __launch_bounds__(WM* WN * 64) void k_gemm(
    const bf16* __restrict__ A, const bf16* __restrict__ Bt, OutT* __restrict__ C,
    int K, int lda, int ldb, int ldc, float alpha, const float* __restrict__ bias,
    long aB, long bB, long cB)
{
  constexpr int NW = WM * WN;
  constexpr int T = NW * 64;
  constexpr int FM = BM / WM / 16;
  constexpr int FN = BN / WN / 16;
  constexpr int CPR = BK / 8;           // 16B chunks per row
  constexpr int CHA = BM * BK / 8;
  constexpr int CHB = BN * BK / 8;
  constexpr int IA = CHA / T;
  constexpr int IB = CHB / T;
  static_assert(CHA % T == 0 && CHB % T == 0, "staging divisibility");

  __shared__ bf16 sA[BM * BK];
  __shared__ bf16 sB[BN * BK];

  const int tid = threadIdx.x;
  const int lane = tid & 63;
  const int wid = tid >> 6;
  const int wm = wid / WN, wn = wid % WN;
  const int bm0 = blockIdx.x * BM;
  const int bn0 = blockIdx.y * BN;
  A += (long)blockIdx.z * aB + (long)bm0 * lda;
  Bt += (long)blockIdx.z * bB + (long)bn0 * ldb;
  C += (long)blockIdx.z * cB;

  f32x4 acc[FM][FN] = {};

  const int lr = lane & 15;
  const int lk = (lane >> 4) * 8;

  for (int k0 = 0; k0 < K; k0 += BK) {
#pragma unroll
    for (int i = 0; i < IA; ++i) {
      int c = i * T + tid;
      int row = c / CPR, kc = (c % CPR) * 8;
      gload16(A + (long)row * lda + k0 + kc, sA + c * 8);
    }
#pragma unroll
    for (int i = 0; i < IB; ++i) {
      int c = i * T + tid;
      int row = c / CPR, kc = (c % CPR) * 8;
      gload16(Bt + (long)row * ldb + k0 + kc, sB + c * 8);
    }
    asm volatile("s_waitcnt vmcnt(0)" ::: "memory");
    __syncthreads();

#pragma unroll
    for (int kk = 0; kk < BK; kk += 32) {
      bf16x8 af[FM], bg[FN];
#pragma unroll
      for (int m = 0; m < FM; ++m) {
        int row = wm * (FM * 16) + m * 16 + lr;
        af[m] = *(const bf16x8*)(sA + row * BK + kk + lk);
      }
#pragma unroll
      for (int n = 0; n < FN; ++n) {
        int col = wn * (FN * 16) + n * 16 + lr;
        bg[n] = *(const bf16x8*)(sB + col * BK + kk + lk);
      }
#pragma unroll
      for (int m = 0; m < FM; ++m)
#pragma unroll
        for (int n = 0; n < FN; ++n)
          acc[m][n] = __builtin_amdgcn_mfma_f32_16x16x32_bf16(af[m], bg[n], acc[m][n], 0, 0, 0);
    }
    __syncthreads();
  }

  const int r0 = (lane >> 4) * 4;
#pragma unroll
  for (int m = 0; m < FM; ++m) {
#pragma unroll
    for (int n = 0; n < FN; ++n) {
      int col = bn0 + wn * (FN * 16) + n * 16 + lr;
      float bv = bias ? bias[col] : 0.f;
#pragma unroll
      for (int r = 0; r < 4; ++r) {
        int row = bm0 + wm * (FM * 16) + m * 16 + r0 + r;
        store_out(C + (long)row * ldc + col, acc[m][n][r] * alpha + bv);
      }
    }
  }
}

// ---------------------------------------------------------------------------
// fp32 -> (fp32 copy, bf16) dual convert, float4-vectorized
__global__ __launch_bounds__(256) void k_cvt_dual(const float* __restrict__ in,
    float* __restrict__ fo, bf16* __restrict__ bo, long n4)
{
  long i = (long)blockIdx.x * 256 + threadIdx.x;
  if (i >= n4) return;
  float4 v = ((const float4*)in)[i];
  ((float4*)fo)[i] = v;
  bf16x4 h; h[0] = (bf16)v.x; h[1] = (bf16)v.y; h[2] = (bf16)v.z; h[3] = (bf16)v.w;
  ((bf16x4*)bo)[i] = h;
}

// transpose + cvt: in [R,C] fp32 -> out [C,R] bf16 (LDS-tiled)
__global__ void k_tr(const float* __restrict__ in, bf16* __restrict__ out, int R, int C)
{
  __shared__ float t[32][33];
  int c0 = blockIdx.x * 32, r0 = blockIdx.y * 32;
#pragma unroll
  for (int i = 0; i < 4; ++i) {
    int r = r0 + threadIdx.y + i * 8;
    t[threadIdx.y + i * 8][threadIdx.x] = in[(long)r * C + c0 + threadIdx.x];
  }
  __syncthreads();
#pragma unroll
  for (int i = 0; i < 4; ++i) {
    int c = c0 + threadIdx.y + i * 8;
    out[(long)c * R + r0 + threadIdx.x] = (bf16)t[threadIdx.x][threadIdx.y + i * 8];
  }
}

// woet[j][d] = sum_h wo[(h*64+d)*512 + j]  (B^T layout of the collapsed wo)
__global__ __launch_bounds__(256) void k_woe(const float* __restrict__ wo, bf16* __restrict__ woet)
{
  int idx = blockIdx.x * 256 + threadIdx.x;   // 32768 total
  int j = idx & 511, d = idx >> 9;
  float s = 0.f;
#pragma unroll
  for (int h = 0; h < 8; ++h) s += wo[(long)(h * 64 + d) * 512 + j];
  woet[(long)j * 64 + d] = (bf16)s;
}

__global__ void k_pack_bias(const float* __restrict__ bq, const float* __restrict__ bk,
                            const float* __restrict__ bv, float* __restrict__ o)
{
  int t = threadIdx.x;
  o[t] = bq[t]; o[64 + t] = bk[t]; o[128 + t] = bv[t];
}

// P = exp(P) elementwise (bf16, x8 vectorized)
__global__ __launch_bounds__(256) void k_exp(bf16* __restrict__ p, long n8)
{
  long i = (long)blockIdx.x * 256 + threadIdx.x;
  if (i >= n8) return;
  bf16x8 v = ((bf16x8*)p)[i];
#pragma unroll
  for (int j = 0; j < 8; ++j) v[j] = (bf16)__expf((float)v[j]);
  ((bf16x8*)p)[i] = v;
}

// cs[b][k] = sum_q P[b][q][k]   (softmax over the q axis!)
__global__ __launch_bounds__(256) void k_colsum(const bf16* __restrict__ P, float* __restrict__ cs)
{
  int k = blockIdx.x * 256 + threadIdx.x;
  int b = blockIdx.y;
  const bf16* p = P + (long)b * S * S + k;
  float a0 = 0, a1 = 0, a2 = 0, a3 = 0;
  for (int q = 0; q < S; q += 4) {
    a0 += (float)p[(long)q * S];
    a1 += (float)p[(long)(q + 1) * S];
    a2 += (float)p[(long)(q + 2) * S];
    a3 += (float)p[(long)(q + 3) * S];
  }
  cs[b * S + k] = (a0 + a1) + (a2 + a3);
}

// vnt[b][d][k] = V[b][k][d] / cs[b][k]; V lives at qkv col 128, ld=192
__global__ __launch_bounds__(256) void k_build_vnt(const bf16* __restrict__ qkv,
    const float* __restrict__ cs, bf16* __restrict__ vnt)
{
  int d = threadIdx.x & 63;
  int k = blockIdx.x * 4 + (threadIdx.x >> 6);
  int b = blockIdx.y;
  float v = (float)qkv[((long)(b * S + k)) * QKVLD + 128 + d];
  vnt[((long)b * HD + d) * S + k] = (bf16)(v / cs[b * S + k]);
}

// y = LN(a + b)*g + be; writes fp32 (fo) and bf16 (bo). One wave per 512-row.
__global__ __launch_bounds__(256) void k_add_ln(const float* __restrict__ a,
    const float* __restrict__ b, const float* __restrict__ g, const float* __restrict__ be,
    float* __restrict__ fo, bf16* __restrict__ bo)
{
  int row = blockIdx.x * 4 + (threadIdx.x >> 6);
  int lane = threadIdx.x & 63;
  const float4* pa = (const float4*)(a + (long)row * D);
  const float4* pb = (const float4*)(b + (long)row * D);
  float4 v[2];
  float s = 0.f, s2 = 0.f;
#pragma unroll
  for (int j = 0; j < 2; ++j) {
    float4 x = pa[lane + j * 64];
    float4 y = pb[lane + j * 64];
    float4 t;
    t.x = x.x + y.x; t.y = x.y + y.y; t.z = x.z + y.z; t.w = x.w + y.w;
    v[j] = t;
    s += t.x + t.y + t.z + t.w;
    s2 += t.x * t.x + t.y * t.y + t.z * t.z + t.w * t.w;
  }
#pragma unroll
  for (int o = 32; o > 0; o >>= 1) { s += __shfl_xor(s, o); s2 += __shfl_xor(s2, o); }
  float mean = s * (1.f / D);
  float var = s2 * (1.f / D) - mean * mean;
  float rstd = rsqrtf(var + 1e-5f);
#pragma unroll
  for (int j = 0; j < 2; ++j) {
    int ci = lane + j * 64;
    float4 gv = ((const float4*)g)[ci];
    float4 bv = ((const float4*)be)[ci];
    float4 t = v[j], y;
    y.x = (t.x - mean) * rstd * gv.x + bv.x;
    y.y = (t.y - mean) * rstd * gv.y + bv.y;
    y.z = (t.z - mean) * rstd * gv.z + bv.z;
    y.w = (t.w - mean) * rstd * gv.w + bv.w;
    ((float4*)(fo + (long)row * D))[ci] = y;
    bf16x4 h; h[0] = (bf16)y.x; h[1] = (bf16)y.y; h[2] = (bf16)y.z; h[3] = (bf16)y.w;
    *(bf16x4*)(bo + (long)row * D + ci * 4) = h;
  }
}

// ---------------------------------------------------------------------------
extern "C" void kernel_launch(void* const* d_in, const int* in_sizes, int n_in,
                              void* d_out, int out_size, void* d_ws, size_t ws_size,
                              hipStream_t stream) {
  const float* x_in = (const float*)d_in[0];
  const float* wq = (const float*)d_in[1];
  const float* bq = (const float*)d_in[2];
  const float* wk = (const float*)d_in[3];
  const float* bk = (const float*)d_in[4];
  const float* wv = (const float*)d_in[5];
  const float* bv = (const float*)d_in[6];
  const float* wo = (const float*)d_in[7];
  const float* bo = (const float*)d_in[8];
  const float* ln_g = (const float*)d_in[9];
  const float* ln_b = (const float*)d_in[10];
  const float* w1 = (const float*)d_in[11];
  const float* b1 = (const float*)d_in[12];
  const float* w2 = (const float*)d_in[13];
  const float* b2 = (const float*)d_in[14];
  float* f_x = (float*)d_out;                       // x master lives in d_out

  char* w = (char*)d_ws;
  size_t off = 0;
  auto alloc = [&](size_t bytes) { void* p = w + off; off += (bytes + 255) & ~(size_t)255; return p; };
  float* f_tmp = (float*)alloc((size_t)BS * D * 4);     // attn-out / ff2
  float* f_h   = (float*)alloc((size_t)BS * D * 4);
  bf16* b_x    = (bf16*)alloc((size_t)BS * D * 2);
  bf16* b_h    = (bf16*)alloc((size_t)BS * D * 2);
  bf16* b_qkv  = (bf16*)alloc((size_t)BS * QKVLD * 2);
  bf16* b_big  = (bf16*)alloc((size_t)BS * FF * 2);     // scores/P then ff1
  float* f_cs  = (float*)alloc((size_t)B * S * 4);
  bf16* b_vnt  = (bf16*)alloc((size_t)B * HD * S * 2);
  bf16* b_head = (bf16*)alloc((size_t)BS * HD * 2);
  bf16* wqkvT  = (bf16*)alloc((size_t)QKVLD * D * 2);   // [192][512]
  bf16* woeT   = (bf16*)alloc((size_t)D * HD * 2);      // [512][64]
  bf16* w1T    = (bf16*)alloc((size_t)FF * D * 2);      // [2048][512]
  bf16* w2T    = (bf16*)alloc((size_t)D * FF * 2);      // [512][2048]
  float* f_bqkv = (float*)alloc(192 * 4);

  // ---- setup (runs every call; weights are tiny) ----
  k_cvt_dual<<<dim3(BS * D / 4 / 256), 256, 0, stream>>>(x_in, f_x, b_x, (long)BS * D / 4);
  k_tr<<<dim3(HD / 32, D / 32), dim3(32, 8), 0, stream>>>(wq, wqkvT, D, HD);
  k_tr<<<dim3(HD / 32, D / 32), dim3(32, 8), 0, stream>>>(wk, wqkvT + 64 * D, D, HD);
  k_tr<<<dim3(HD / 32, D / 32), dim3(32, 8), 0, stream>>>(wv, wqkvT + 128 * D, D, HD);
  k_tr<<<dim3(FF / 32, D / 32), dim3(32, 8), 0, stream>>>(w1, w1T, D, FF);
  k_tr<<<dim3(D / 32, FF / 32), dim3(32, 8), 0, stream>>>(w2, w2T, FF, D);
  k_woe<<<dim3(128), 256, 0, stream>>>(wo, woeT);
  k_pack_bias<<<1, 64, 0, stream>>>(bq, bk, bv, f_bqkv);

  for (int layer = 0; layer < 4; ++layer) {
    // fused QKV projection: [16384,512] x [192,512]^T -> [16384,192]
    k_gemm<128, 64, 64, 4, 1, bf16><<<dim3(BS / 128, 3, 1), 256, 0, stream>>>(
        b_x, wqkvT, b_qkv, D, D, D, QKVLD, 1.f, f_bqkv, 0, 0, 0);
    // scores = Q K^T / 8, per batch  -> b_big (bf16)
    k_gemm<128, 128, 64, 2, 2, bf16><<<dim3(S / 128, S / 128, B), 256, 0, stream>>>(
        b_qkv, b_qkv + 64, b_big, HD, QKVLD, QKVLD, S, 0.125f, nullptr,
        (long)S * QKVLD, (long)S * QKVLD, (long)S * S);
    // P = exp(scores); colsum over q; fold 1/colsum into V^T
    k_exp<<<dim3((int)((long)B * S * S / 8 / 256)), 256, 0, stream>>>(b_big, (long)B * S * S / 8);
    k_colsum<<<dim3(S / 256, B), 256, 0, stream>>>(b_big, f_cs);
    k_build_vnt<<<dim3(S / 4, B), 256, 0, stream>>>(b_qkv, f_cs, b_vnt);
    // head = P @ Vn, per batch -> b_head (bf16)
    k_gemm<128, 64, 64, 4, 1, bf16><<<dim3(S / 128, 1, B), 256, 0, stream>>>(
        b_big, b_vnt, b_head, S, S, S, HD, 1.f, nullptr,
        (long)S * S, (long)HD * S, (long)S * HD);
    // out = head @ wo_eff + bo -> f_tmp (fp32)
    k_gemm<128, 128, 64, 2, 2, float><<<dim3(BS / 128, D / 128, 1), 256, 0, stream>>>(
        b_head, woeT, f_tmp, HD, HD, HD, D, 1.f, bo, 0, 0, 0);
    // h = LN(attn + x)
    k_add_ln<<<dim3(BS / 4), 256, 0, stream>>>(f_tmp, f_x, ln_g, ln_b, f_h, b_h);
    // ff1 = h @ w1 + b1 -> b_big (bf16)
    k_gemm<128, 128, 64, 2, 2, bf16><<<dim3(BS / 128, FF / 128, 1), 256, 0, stream>>>(
        b_h, w1T, b_big, D, D, D, FF, 1.f, b1, 0, 0, 0);
    // ff2 = ff1 @ w2 + b2 -> f_tmp (fp32)
    k_gemm<128, 128, 64, 2, 2, float><<<dim3(BS / 128, D / 128, 1), 256, 0, stream>>>(
        b_big, w2T, f_tmp, FF, FF, FF, D, 1.f, b2, 0, 0, 0);
    // x = LN(h + ff2)  (writes d_out fp32 + b_x bf16)
    k_add_ln<<<dim3(BS / 4), 256, 0, stream>>>(f_tmp, f_h, ln_g, ln_b, f_x, b_x);
  }
}

// Round 3
// 1018.346 us; speedup vs baseline: 1.1265x; 1.1265x over previous
//
#include <hip/hip_runtime.h>
#include <hip/hip_bf16.h>

#define DEV __device__ __forceinline__

typedef __bf16 bf16;
typedef __attribute__((ext_vector_type(8))) __bf16 bf16x8;
typedef __attribute__((ext_vector_type(4))) __bf16 bf16x4;
typedef __attribute__((ext_vector_type(4))) float f32x4;

static constexpr int B = 16, S = 1024, D = 512, HD = 64, FF = 2048;
static constexpr int BS = B * S;
static constexpr int QKVLD = 192;

typedef const __attribute__((address_space(1))) void gas_void;
typedef __attribute__((address_space(3))) void las_void;

DEV void gload16(const void* g, void* l) {
  __builtin_amdgcn_global_load_lds((gas_void*)g, (las_void*)l, 16, 0, 0);
}

DEV void store_out(float* p, float v) { *p = v; }
DEV void store_out(bf16* p, float v) { *p = (bf16)v; }

#define MEMFENCE asm volatile("" ::: "memory")
#define VMCNT(n) asm volatile("s_waitcnt vmcnt(" #n ")" ::: "memory")

// ===========================================================================
// 8-phase 256-wide-N GEMM (T1+T2+T3+T4+T5).  C[M,N] = A[M,K] * Bt[N,K]^T.
// BM in {128,256}, BN=256, BK=64, 8 waves (2M x 4N), 512 threads.
// Wave (wm,wn) owns scattered quadrants: rows qm*HM + wm*(HM/2) + fm*16,
// cols qn*128 + wn*32 + fn*16.  LDS halves: A: [2 buf][2 half][HM*64],
// B: [2 buf][2 half][128*64].  XOR-involution swizzle on 16B chunks within
// each row (c' = c ^ (row&7)) applied at the GLOBAL source (linear LDS dest,
// rule #21) and on ds_read addresses.
// Phase p reads (qm,qn) of one buf; prefetches one half-tile that died one
// phase earlier; counted vmcnt at phases 4 and 8 only.
// ===========================================================================
template<int BM, typename OutT>
__global__ __launch_bounds__(512, 1) void k_gemm8p(
    const bf16* __restrict__ A, const bf16* __restrict__ Bt, OutT* __restrict__ C,
    int K, int lda, int ldb, int ldc, int gn, float alpha, const float* __restrict__ bias)
{
  static_assert(BM == 128 || BM == 256, "");
  constexpr int HM = BM / 2;           // rows per A-half
  constexpr int FMH = HM / 2 / 16;     // A frags per wave per half (256->4, 128->2)
  constexpr int GL_A = HM / 64;        // gload issues per A-half (2 or 1)
  constexpr int GL_B = 2;              // gload issues per B-half (128*64*2B / 8KB)

  __shared__ bf16 sA[2][2][HM * 64];
  __shared__ bf16 sB[2][2][128 * 64];

  const int tid = threadIdx.x;
  const int lane = tid & 63;
  const int wid = tid >> 6;
  const int wm = wid >> 2;             // 0..1
  const int wn = wid & 3;              // 0..3
  const int lr = lane & 15;
  const int lk8 = (lane >> 4) * 8;

  // XCD-bijective remap (nwg % 8 == 0 guaranteed by launch config)
  const int nwg = gridDim.x;
  const int bid = blockIdx.x;
  const int swz = (bid & 7) * (nwg >> 3) + (bid >> 3);
  const int im = swz / gn, in = swz % gn;
  const int bm0 = im * BM, bn0 = in * 256;

  A += (long)bm0 * lda;
  Bt += (long)bn0 * ldb;

  const int NT = K >> 6;               // K-tiles (BK=64); requires K%128==0
  const int NI = NT >> 1;

  auto stageA = [&](int buf, int h, int t) {
    if (t >= NT) return;
    const bf16* src = A + (long)t * 64;
#pragma unroll
    for (int it = 0; it < GL_A; ++it) {
      int c = it * 512 + tid;
      int row = c >> 3;
      int cc = (c & 7) ^ (row & 7);
      gload16(src + (long)(h * HM + row) * lda + cc * 8, &sA[buf][h][c * 8]);
    }
  };
  auto stageB = [&](int buf, int h, int t) {
    if (t >= NT) return;
    const bf16* src = Bt + (long)t * 64;
#pragma unroll
    for (int it = 0; it < GL_B; ++it) {
      int c = it * 512 + tid;
      int row = c >> 3;
      int cc = (c & 7) ^ (row & 7);
      gload16(src + (long)(h * 128 + row) * ldb + cc * 8, &sB[buf][h][c * 8]);
    }
  };

  f32x4 acc[4][FMH * 2] = {};

  // ---- prologue: tile0 fully into buf0; tile1's Ah0,Bh1 into buf1 ----
  stageA(0, 0, 0); stageB(0, 1, 0); stageA(0, 1, 0); stageB(0, 0, 0);
  stageA(1, 0, 1); stageB(1, 1, 1);
  if (GL_A == 2) { VMCNT(4); } else { VMCNT(3); }
  MEMFENCE; __builtin_amdgcn_s_barrier(); MEMFENCE;

#define PHASE(b, qm, qn, STAGE, ...) do {                                        \
    bf16x8 af[FMH][2], bg[2][2];                                                 \
    _Pragma("unroll") for (int fm = 0; fm < FMH; ++fm)                           \
    _Pragma("unroll") for (int kx = 0; kx < 2; ++kx) {                           \
      int ra = wm * (HM / 2) + fm * 16 + lr;                                     \
      int e = kx * 32 + lk8;                                                     \
      af[fm][kx] = *(const bf16x8*)((const char*)&sA[b][qm][0] +                 \
                     (ra * 8 + ((e >> 3) ^ (ra & 7))) * 16);                     \
    }                                                                            \
    _Pragma("unroll") for (int fn = 0; fn < 2; ++fn)                             \
    _Pragma("unroll") for (int kx = 0; kx < 2; ++kx) {                           \
      int rb = wn * 32 + fn * 16 + lr;                                           \
      int e = kx * 32 + lk8;                                                     \
      bg[fn][kx] = *(const bf16x8*)((const char*)&sB[b][qn][0] +                 \
                     (rb * 8 + ((e >> 3) ^ (rb & 7))) * 16);                     \
    }                                                                            \
    STAGE;                                                                       \
    MEMFENCE; __builtin_amdgcn_s_barrier(); MEMFENCE;                            \
    __builtin_amdgcn_s_setprio(1);                                               \
    _Pragma("unroll") for (int kx = 0; kx < 2; ++kx)                             \
    _Pragma("unroll") for (int fm = 0; fm < FMH; ++fm)                           \
    _Pragma("unroll") for (int fn = 0; fn < 2; ++fn)                             \
      acc[qm * 2 + qn][fm * 2 + fn] = __builtin_amdgcn_mfma_f32_16x16x32_bf16(   \
          af[fm][kx], bg[fn][kx], acc[qm * 2 + qn][fm * 2 + fn], 0, 0, 0);       \
    __builtin_amdgcn_s_setprio(0);                                               \
    __VA_ARGS__;                                                                 \
    MEMFENCE; __builtin_amdgcn_s_barrier(); MEMFENCE;                            \
  } while (0)

  for (int i = 0; i < NI; ++i) {
    const int t1 = 2 * i + 1, t2 = 2 * i + 2, t3 = 2 * i + 3;
    const bool more = (t2 < NT);
    // buf0 compute (tile 2i); deaths: Ah0@p2, Bh1@p3, Ah1@p4, Bh0@p4
    PHASE(0, 0, 0, stageA(1, 1, t1));
    PHASE(0, 0, 1, stageB(1, 0, t1));
    PHASE(0, 1, 1, stageA(0, 0, t2));
    PHASE(0, 1, 0, stageB(0, 1, t2),
          if (more) { if (GL_A == 2) { VMCNT(4); } else { VMCNT(3); } }
          else { VMCNT(0); });
    // buf1 compute (tile 2i+1); deaths: Ah0@p6, Bh1@p7, Ah1@p8, Bh0@p8
    PHASE(1, 0, 0, stageA(0, 1, t2));
    PHASE(1, 0, 1, stageB(0, 0, t2));
    PHASE(1, 1, 1, stageA(1, 0, t3));
    PHASE(1, 1, 0, stageB(1, 1, t3),
          if (more) { if (GL_A == 2) { VMCNT(4); } else { VMCNT(3); } });
  }
#undef PHASE

  // ---- epilogue ----
  const int r0 = (lane >> 4) * 4;
#pragma unroll
  for (int qm = 0; qm < 2; ++qm)
#pragma unroll
  for (int qn = 0; qn < 2; ++qn)
#pragma unroll
  for (int fm = 0; fm < FMH; ++fm)
#pragma unroll
  for (int fn = 0; fn < 2; ++fn) {
    int gc = bn0 + qn * 128 + wn * 32 + fn * 16 + lr;
    float bv = bias ? bias[gc] : 0.f;
#pragma unroll
    for (int r = 0; r < 4; ++r) {
      int gr = bm0 + qm * HM + wm * (HM / 2) + fm * 16 + r0 + r;
      store_out(C + (long)gr * ldc + gc, acc[qm * 2 + qn][fm * 2 + fn][r] * alpha + bv);
    }
  }
}

// ---------------------------------------------------------------------------
// Simple single-buffered MFMA GEMM (shallow-K / small shapes). Optional EXP
// fused into the epilogue (for the q-axis-softmax scores).
// ---------------------------------------------------------------------------
template<int BM, int BN, int BK, int WM, int WN, typename OutT, bool EXPF>
__global__ __launch_bounds__(WM* WN * 64) void k_gemm(
    const bf16* __restrict__ A, const bf16* __restrict__ Bt, OutT* __restrict__ C,
    int K, int lda, int ldb, int ldc, float alpha, const float* __restrict__ bias,
    long aB, long bB, long cB)
{
  constexpr int NW = WM * WN;
  constexpr int T = NW * 64;
  constexpr int FM = BM / WM / 16;
  constexpr int FN = BN / WN / 16;
  constexpr int CPR = BK / 8;
  constexpr int CHA = BM * BK / 8;
  constexpr int CHB = BN * BK / 8;
  constexpr int IA = CHA / T;
  constexpr int IB = CHB / T;
  static_assert(CHA % T == 0 && CHB % T == 0, "staging divisibility");

  __shared__ bf16 sA[BM * BK];
  __shared__ bf16 sB[BN * BK];

  const int tid = threadIdx.x;
  const int lane = tid & 63;
  const int wid = tid >> 6;
  const int wm = wid / WN, wn = wid % WN;
  const int bm0 = blockIdx.x * BM;
  const int bn0 = blockIdx.y * BN;
  A += (long)blockIdx.z * aB + (long)bm0 * lda;
  Bt += (long)blockIdx.z * bB + (long)bn0 * ldb;
  C += (long)blockIdx.z * cB;

  f32x4 acc[FM][FN] = {};
  const int lr = lane & 15;
  const int lk = (lane >> 4) * 8;

  for (int k0 = 0; k0 < K; k0 += BK) {
#pragma unroll
    for (int i = 0; i < IA; ++i) {
      int c = i * T + tid;
      int row = c / CPR, kc = (c % CPR) * 8;
      gload16(A + (long)row * lda + k0 + kc, sA + c * 8);
    }
#pragma unroll
    for (int i = 0; i < IB; ++i) {
      int c = i * T + tid;
      int row = c / CPR, kc = (c % CPR) * 8;
      gload16(Bt + (long)row * ldb + k0 + kc, sB + c * 8);
    }
    asm volatile("s_waitcnt vmcnt(0)" ::: "memory");
    __syncthreads();

#pragma unroll
    for (int kk = 0; kk < BK; kk += 32) {
      bf16x8 af[FM], bg[FN];
#pragma unroll
      for (int m = 0; m < FM; ++m) {
        int row = wm * (FM * 16) + m * 16 + lr;
        af[m] = *(const bf16x8*)(sA + row * BK + kk + lk);
      }
#pragma unroll
      for (int n = 0; n < FN; ++n) {
        int col = wn * (FN * 16) + n * 16 + lr;
        bg[n] = *(const bf16x8*)(sB + col * BK + kk + lk);
      }
#pragma unroll
      for (int m = 0; m < FM; ++m)
#pragma unroll
        for (int n = 0; n < FN; ++n)
          acc[m][n] = __builtin_amdgcn_mfma_f32_16x16x32_bf16(af[m], bg[n], acc[m][n], 0, 0, 0);
    }
    __syncthreads();
  }

  const int r0 = (lane >> 4) * 4;
#pragma unroll
  for (int m = 0; m < FM; ++m) {
#pragma unroll
    for (int n = 0; n < FN; ++n) {
      int col = bn0 + wn * (FN * 16) + n * 16 + lr;
      float bv = bias ? bias[col] : 0.f;
#pragma unroll
      for (int r = 0; r < 4; ++r) {
        int row = bm0 + wm * (FM * 16) + m * 16 + r0 + r;
        float v = acc[m][n][r] * alpha + bv;
        if (EXPF) v = __expf(v);
        store_out(C + (long)row * ldc + col, v);
      }
    }
  }
}

// ---------------------------------------------------------------------------
__global__ __launch_bounds__(256) void k_cvt_dual(const float* __restrict__ in,
    float* __restrict__ fo, bf16* __restrict__ bo, long n4)
{
  long i = (long)blockIdx.x * 256 + threadIdx.x;
  if (i >= n4) return;
  float4 v = ((const float4*)in)[i];
  ((float4*)fo)[i] = v;
  bf16x4 h; h[0] = (bf16)v.x; h[1] = (bf16)v.y; h[2] = (bf16)v.z; h[3] = (bf16)v.w;
  ((bf16x4*)bo)[i] = h;
}

__global__ void k_tr(const float* __restrict__ in, bf16* __restrict__ out, int R, int C)
{
  __shared__ float t[32][33];
  int c0 = blockIdx.x * 32, r0 = blockIdx.y * 32;
#pragma unroll
  for (int i = 0; i < 4; ++i) {
    int r = r0 + threadIdx.y + i * 8;
    t[threadIdx.y + i * 8][threadIdx.x] = in[(long)r * C + c0 + threadIdx.x];
  }
  __syncthreads();
#pragma unroll
  for (int i = 0; i < 4; ++i) {
    int c = c0 + threadIdx.y + i * 8;
    out[(long)c * R + r0 + threadIdx.x] = (bf16)t[threadIdx.x][threadIdx.y + i * 8];
  }
}

__global__ __launch_bounds__(256) void k_woe(const float* __restrict__ wo, bf16* __restrict__ woet)
{
  int idx = blockIdx.x * 256 + threadIdx.x;
  int j = idx & 511, d = idx >> 9;
  float s = 0.f;
#pragma unroll
  for (int h = 0; h < 8; ++h) s += wo[(long)(h * 64 + d) * 512 + j];
  woet[(long)j * 64 + d] = (bf16)s;
}

__global__ void k_pack_bias(const float* __restrict__ bq, const float* __restrict__ bk,
                            const float* __restrict__ bv, float* __restrict__ o)
{
  int t = threadIdx.x;
  o[t] = bq[t]; o[64 + t] = bk[t]; o[128 + t] = bv[t];
}

__global__ __launch_bounds__(256) void k_colsum(const bf16* __restrict__ P, float* __restrict__ cs)
{
  int k = blockIdx.x * 256 + threadIdx.x;
  int b = blockIdx.y;
  const bf16* p = P + (long)b * S * S + k;
  float a0 = 0, a1 = 0, a2 = 0, a3 = 0;
  for (int q = 0; q < S; q += 4) {
    a0 += (float)p[(long)q * S];
    a1 += (float)p[(long)(q + 1) * S];
    a2 += (float)p[(long)(q + 2) * S];
    a3 += (float)p[(long)(q + 3) * S];
  }
  cs[b * S + k] = (a0 + a1) + (a2 + a3);
}

__global__ __launch_bounds__(256) void k_build_vnt(const bf16* __restrict__ qkv,
    const float* __restrict__ cs, bf16* __restrict__ vnt)
{
  int d = threadIdx.x & 63;
  int k = blockIdx.x * 4 + (threadIdx.x >> 6);
  int b = blockIdx.y;
  float v = (float)qkv[((long)(b * S + k)) * QKVLD + 128 + d];
  vnt[((long)b * HD + d) * S + k] = (bf16)(v / cs[b * S + k]);
}

__global__ __launch_bounds__(256) void k_add_ln(const float* __restrict__ a,
    const float* __restrict__ b, const float* __restrict__ g, const float* __restrict__ be,
    float* __restrict__ fo, bf16* __restrict__ bo)
{
  int row = blockIdx.x * 4 + (threadIdx.x >> 6);
  int lane = threadIdx.x & 63;
  const float4* pa = (const float4*)(a + (long)row * D);
  const float4* pb = (const float4*)(b + (long)row * D);
  float4 v[2];
  float s = 0.f, s2 = 0.f;
#pragma unroll
  for (int j = 0; j < 2; ++j) {
    float4 x = pa[lane + j * 64];
    float4 y = pb[lane + j * 64];
    float4 t;
    t.x = x.x + y.x; t.y = x.y + y.y; t.z = x.z + y.z; t.w = x.w + y.w;
    v[j] = t;
    s += t.x + t.y + t.z + t.w;
    s2 += t.x * t.x + t.y * t.y + t.z * t.z + t.w * t.w;
  }
#pragma unroll
  for (int o = 32; o > 0; o >>= 1) { s += __shfl_xor(s, o); s2 += __shfl_xor(s2, o); }
  float mean = s * (1.f / D);
  float var = s2 * (1.f / D) - mean * mean;
  float rstd = rsqrtf(var + 1e-5f);
#pragma unroll
  for (int j = 0; j < 2; ++j) {
    int ci = lane + j * 64;
    float4 gv = ((const float4*)g)[ci];
    float4 bv = ((const float4*)be)[ci];
    float4 t = v[j], y;
    y.x = (t.x - mean) * rstd * gv.x + bv.x;
    y.y = (t.y - mean) * rstd * gv.y + bv.y;
    y.z = (t.z - mean) * rstd * gv.z + bv.z;
    y.w = (t.w - mean) * rstd * gv.w + bv.w;
    ((float4*)(fo + (long)row * D))[ci] = y;
    bf16x4 h; h[0] = (bf16)y.x; h[1] = (bf16)y.y; h[2] = (bf16)y.z; h[3] = (bf16)y.w;
    *(bf16x4*)(bo + (long)row * D + ci * 4) = h;
  }
}

// ---------------------------------------------------------------------------
extern "C" void kernel_launch(void* const* d_in, const int* in_sizes, int n_in,
                              void* d_out, int out_size, void* d_ws, size_t ws_size,
                              hipStream_t stream) {
  const float* x_in = (const float*)d_in[0];
  const float* wq = (const float*)d_in[1];
  const float* bq = (const float*)d_in[2];
  const float* wk = (const float*)d_in[3];
  const float* bk = (const float*)d_in[4];
  const float* wv = (const float*)d_in[5];
  const float* bv = (const float*)d_in[6];
  const float* wo = (const float*)d_in[7];
  const float* bo = (const float*)d_in[8];
  const float* ln_g = (const float*)d_in[9];
  const float* ln_b = (const float*)d_in[10];
  const float* w1 = (const float*)d_in[11];
  const float* b1 = (const float*)d_in[12];
  const float* w2 = (const float*)d_in[13];
  const float* b2 = (const float*)d_in[14];
  float* f_x = (float*)d_out;

  char* w = (char*)d_ws;
  size_t off = 0;
  auto alloc = [&](size_t bytes) { void* p = w + off; off += (bytes + 255) & ~(size_t)255; return p; };
  float* f_tmp = (float*)alloc((size_t)BS * D * 4);
  float* f_h   = (float*)alloc((size_t)BS * D * 4);
  bf16* b_x    = (bf16*)alloc((size_t)BS * D * 2);
  bf16* b_h    = (bf16*)alloc((size_t)BS * D * 2);
  bf16* b_qkv  = (bf16*)alloc((size_t)BS * QKVLD * 2);
  bf16* b_big  = (bf16*)alloc((size_t)BS * FF * 2);
  float* f_cs  = (float*)alloc((size_t)B * S * 4);
  bf16* b_vnt  = (bf16*)alloc((size_t)B * HD * S * 2);
  bf16* b_head = (bf16*)alloc((size_t)BS * HD * 2);
  bf16* wqkvT  = (bf16*)alloc((size_t)QKVLD * D * 2);
  bf16* woeT   = (bf16*)alloc((size_t)D * HD * 2);
  bf16* w1T    = (bf16*)alloc((size_t)FF * D * 2);
  bf16* w2T    = (bf16*)alloc((size_t)D * FF * 2);
  float* f_bqkv = (float*)alloc(192 * 4);

  // ---- setup ----
  k_cvt_dual<<<dim3(BS * D / 4 / 256), 256, 0, stream>>>(x_in, f_x, b_x, (long)BS * D / 4);
  k_tr<<<dim3(HD / 32, D / 32), dim3(32, 8), 0, stream>>>(wq, wqkvT, D, HD);
  k_tr<<<dim3(HD / 32, D / 32), dim3(32, 8), 0, stream>>>(wk, wqkvT + 64 * D, D, HD);
  k_tr<<<dim3(HD / 32, D / 32), dim3(32, 8), 0, stream>>>(wv, wqkvT + 128 * D, D, HD);
  k_tr<<<dim3(FF / 32, D / 32), dim3(32, 8), 0, stream>>>(w1, w1T, D, FF);
  k_tr<<<dim3(D / 32, FF / 32), dim3(32, 8), 0, stream>>>(w2, w2T, FF, D);
  k_woe<<<dim3(128), 256, 0, stream>>>(wo, woeT);
  k_pack_bias<<<1, 64, 0, stream>>>(bq, bk, bv, f_bqkv);

  for (int layer = 0; layer < 4; ++layer) {
    // fused QKV projection
    k_gemm<128, 64, 64, 4, 1, bf16, false><<<dim3(BS / 128, 3, 1), 256, 0, stream>>>(
        b_x, wqkvT, b_qkv, D, D, D, QKVLD, 1.f, f_bqkv, 0, 0, 0);
    // P = exp(Q K^T / 8) fused
    k_gemm<128, 128, 64, 2, 2, bf16, true><<<dim3(S / 128, S / 128, B), 256, 0, stream>>>(
        b_qkv, b_qkv + 64, b_big, HD, QKVLD, QKVLD, S, 0.125f, nullptr,
        (long)S * QKVLD, (long)S * QKVLD, (long)S * S);
    // colsum over q; fold 1/colsum into V^T
    k_colsum<<<dim3(S / 256, B), 256, 0, stream>>>(b_big, f_cs);
    k_build_vnt<<<dim3(S / 4, B), 256, 0, stream>>>(b_qkv, f_cs, b_vnt);
    // head = P @ Vn  (64-tile: 256 blocks for occupancy)
    k_gemm<64, 64, 64, 4, 1, bf16, false><<<dim3(S / 64, 1, B), 256, 0, stream>>>(
        b_big, b_vnt, b_head, S, S, S, HD, 1.f, nullptr,
        (long)S * S, (long)HD * S, (long)S * HD);
    // out = head @ wo_eff + bo
    k_gemm<128, 128, 64, 2, 2, float, false><<<dim3(BS / 128, D / 128, 1), 256, 0, stream>>>(
        b_head, woeT, f_tmp, HD, HD, HD, D, 1.f, bo, 0, 0, 0);
    // h = LN(attn + x)
    k_add_ln<<<dim3(BS / 4), 256, 0, stream>>>(f_tmp, f_x, ln_g, ln_b, f_h, b_h);
    // ff1 = h @ w1 + b1   (8-phase, 256x256, grid 64x8=512)
    k_gemm8p<256, bf16><<<dim3((BS / 256) * (FF / 256)), 512, 0, stream>>>(
        b_h, w1T, b_big, D, D, D, FF, FF / 256, 1.f, b1);
    // ff2 = ff1 @ w2 + b2 (8-phase, 128x256, grid 128x2=256)
    k_gemm8p<128, float><<<dim3((BS / 128) * (D / 256)), 512, 0, stream>>>(
        b_big, w2T, f_tmp, FF, FF, FF, D, D / 256, 1.f, b2);
    // x = LN(h + ff2)
    k_add_ln<<<dim3(BS / 4), 256, 0, stream>>>(f_tmp, f_h, ln_g, ln_b, f_x, b_x);
  }
}

// Round 4
// 980.719 us; speedup vs baseline: 1.1697x; 1.0384x over previous
//
#include <hip/hip_runtime.h>
#include <hip/hip_bf16.h>

#define DEV __device__ __forceinline__

typedef __bf16 bf16;
typedef __attribute__((ext_vector_type(8))) __bf16 bf16x8;
typedef __attribute__((ext_vector_type(4))) __bf16 bf16x4;
typedef __attribute__((ext_vector_type(4))) float f32x4;

static constexpr int B = 16, S = 1024, D = 512, HD = 64, FF = 2048;
static constexpr int BS = B * S;
static constexpr int QKVLD = 192;

typedef const __attribute__((address_space(1))) void gas_void;
typedef __attribute__((address_space(3))) void las_void;

DEV void gload16(const void* g, void* l) {
  __builtin_amdgcn_global_load_lds((gas_void*)g, (las_void*)l, 16, 0, 0);
}

DEV void store_out(float* p, float v) { *p = v; }
DEV void store_out(bf16* p, float v) { *p = (bf16)v; }

#define MEMFENCE asm volatile("" ::: "memory")
#define VMCNT(n) asm volatile("s_waitcnt vmcnt(" #n ")" ::: "memory")

// ===========================================================================
// 8-phase 256x256 GEMM (T1+T2+T3+T4+T5) — used for ff1 only.
// ===========================================================================
template<int BM, typename OutT>
__global__ __launch_bounds__(512, 1) void k_gemm8p(
    const bf16* __restrict__ A, const bf16* __restrict__ Bt, OutT* __restrict__ C,
    int K, int lda, int ldb, int ldc, int gn, float alpha, const float* __restrict__ bias)
{
  static_assert(BM == 128 || BM == 256, "");
  constexpr int HM = BM / 2;
  constexpr int FMH = HM / 2 / 16;
  constexpr int GL_A = HM / 64;
  constexpr int GL_B = 2;

  __shared__ bf16 sA[2][2][HM * 64];
  __shared__ bf16 sB[2][2][128 * 64];

  const int tid = threadIdx.x;
  const int lane = tid & 63;
  const int wid = tid >> 6;
  const int wm = wid >> 2;
  const int wn = wid & 3;
  const int lr = lane & 15;
  const int lk8 = (lane >> 4) * 8;

  const int nwg = gridDim.x;
  const int bid = blockIdx.x;
  const int swz = (bid & 7) * (nwg >> 3) + (bid >> 3);
  const int im = swz / gn, in = swz % gn;
  const int bm0 = im * BM, bn0 = in * 256;

  A += (long)bm0 * lda;
  Bt += (long)bn0 * ldb;

  const int NT = K >> 6;
  const int NI = NT >> 1;

  auto stageA = [&](int buf, int h, int t) {
    if (t >= NT) return;
    const bf16* src = A + (long)t * 64;
#pragma unroll
    for (int it = 0; it < GL_A; ++it) {
      int c = it * 512 + tid;
      int row = c >> 3;
      int cc = (c & 7) ^ (row & 7);
      gload16(src + (long)(h * HM + row) * lda + cc * 8, &sA[buf][h][c * 8]);
    }
  };
  auto stageB = [&](int buf, int h, int t) {
    if (t >= NT) return;
    const bf16* src = Bt + (long)t * 64;
#pragma unroll
    for (int it = 0; it < GL_B; ++it) {
      int c = it * 512 + tid;
      int row = c >> 3;
      int cc = (c & 7) ^ (row & 7);
      gload16(src + (long)(h * 128 + row) * ldb + cc * 8, &sB[buf][h][c * 8]);
    }
  };

  f32x4 acc[4][FMH * 2] = {};

  stageA(0, 0, 0); stageB(0, 1, 0); stageA(0, 1, 0); stageB(0, 0, 0);
  stageA(1, 0, 1); stageB(1, 1, 1);
  if (GL_A == 2) { VMCNT(4); } else { VMCNT(3); }
  MEMFENCE; __builtin_amdgcn_s_barrier(); MEMFENCE;

#define PHASE(b, qm, qn, STAGE, ...) do {                                        \
    bf16x8 af[FMH][2], bg[2][2];                                                 \
    _Pragma("unroll") for (int fm = 0; fm < FMH; ++fm)                           \
    _Pragma("unroll") for (int kx = 0; kx < 2; ++kx) {                           \
      int ra = wm * (HM / 2) + fm * 16 + lr;                                     \
      int e = kx * 32 + lk8;                                                     \
      af[fm][kx] = *(const bf16x8*)((const char*)&sA[b][qm][0] +                 \
                     (ra * 8 + ((e >> 3) ^ (ra & 7))) * 16);                     \
    }                                                                            \
    _Pragma("unroll") for (int fn = 0; fn < 2; ++fn)                             \
    _Pragma("unroll") for (int kx = 0; kx < 2; ++kx) {                           \
      int rb = wn * 32 + fn * 16 + lr;                                           \
      int e = kx * 32 + lk8;                                                     \
      bg[fn][kx] = *(const bf16x8*)((const char*)&sB[b][qn][0] +                 \
                     (rb * 8 + ((e >> 3) ^ (rb & 7))) * 16);                     \
    }                                                                            \
    STAGE;                                                                       \
    MEMFENCE; __builtin_amdgcn_s_barrier(); MEMFENCE;                            \
    __builtin_amdgcn_s_setprio(1);                                               \
    _Pragma("unroll") for (int kx = 0; kx < 2; ++kx)                             \
    _Pragma("unroll") for (int fm = 0; fm < FMH; ++fm)                           \
    _Pragma("unroll") for (int fn = 0; fn < 2; ++fn)                             \
      acc[qm * 2 + qn][fm * 2 + fn] = __builtin_amdgcn_mfma_f32_16x16x32_bf16(   \
          af[fm][kx], bg[fn][kx], acc[qm * 2 + qn][fm * 2 + fn], 0, 0, 0);       \
    __builtin_amdgcn_s_setprio(0);                                               \
    __VA_ARGS__;                                                                 \
    MEMFENCE; __builtin_amdgcn_s_barrier(); MEMFENCE;                            \
  } while (0)

  for (int i = 0; i < NI; ++i) {
    const int t1 = 2 * i + 1, t2 = 2 * i + 2, t3 = 2 * i + 3;
    const bool more = (t2 < NT);
    PHASE(0, 0, 0, stageA(1, 1, t1));
    PHASE(0, 0, 1, stageB(1, 0, t1));
    PHASE(0, 1, 1, stageA(0, 0, t2));
    PHASE(0, 1, 0, stageB(0, 1, t2),
          if (more) { if (GL_A == 2) { VMCNT(4); } else { VMCNT(3); } }
          else { VMCNT(0); });
    PHASE(1, 0, 0, stageA(0, 1, t2));
    PHASE(1, 0, 1, stageB(0, 0, t2));
    PHASE(1, 1, 1, stageA(1, 0, t3));
    PHASE(1, 1, 0, stageB(1, 1, t3),
          if (more) { if (GL_A == 2) { VMCNT(4); } else { VMCNT(3); } });
  }
#undef PHASE

  const int r0 = (lane >> 4) * 4;
#pragma unroll
  for (int qm = 0; qm < 2; ++qm)
#pragma unroll
  for (int qn = 0; qn < 2; ++qn)
#pragma unroll
  for (int fm = 0; fm < FMH; ++fm)
#pragma unroll
  for (int fn = 0; fn < 2; ++fn) {
    int gc = bn0 + qn * 128 + wn * 32 + fn * 16 + lr;
    float bv = bias ? bias[gc] : 0.f;
#pragma unroll
    for (int r = 0; r < 4; ++r) {
      int gr = bm0 + qm * HM + wm * (HM / 2) + fm * 16 + r0 + r;
      store_out(C + (long)gr * ldc + gc, acc[qm * 2 + qn][fm * 2 + fn][r] * alpha + bv);
    }
  }
}

// ===========================================================================
// Fused GEMM (+bias) + residual-add + LayerNorm.  BM=64 rows, BN=512=D (full
// rows per block -> in-block row reduction).  A:[M,K] bf16, Bt:[512,K] bf16,
// resid fp32 [M,512].  Writes fo fp32 + bo16 bf16.  8 waves: wm=wid>>1 row
// group (16 rows), wn=wid&1 col half (256).  NT = K/64; DB = double-buffer.
// ===========================================================================
template<int NT, bool DB>
__global__ __launch_bounds__(512, 2) void k_gemm_ln(
    const bf16* __restrict__ A, const bf16* __restrict__ Bt,
    const float* __restrict__ resid, const float* __restrict__ bias,
    const float* __restrict__ g, const float* __restrict__ be,
    float* __restrict__ fo, bf16* __restrict__ bo16)
{
  constexpr int K = NT * 64;
  constexpr int NB = DB ? 2 : 1;
  __shared__ bf16 sA[NB][64 * 64];
  __shared__ bf16 sB[NB][512 * 64];
  __shared__ float lsum[2][64][2];

  const int tid = threadIdx.x;
  const int lane = tid & 63;
  const int wid = tid >> 6;
  const int wm = wid >> 1;
  const int wn = wid & 1;
  const int lr = lane & 15;
  const int lk8 = (lane >> 4) * 8;
  const long bm0 = (long)blockIdx.x * 64;

  const bf16* Ab = A + bm0 * K;

  auto stage = [&](int buf, int t) {
    {
      int c = tid;                     // A: 512 chunks of 16B
      int row = c >> 3;
      int cc = (c & 7) ^ (row & 7);
      gload16(Ab + (long)row * K + t * 64 + cc * 8, &sA[buf][c * 8]);
    }
#pragma unroll
    for (int it = 0; it < 8; ++it) {   // B: 4096 chunks
      int c = it * 512 + tid;
      int row = c >> 3;
      int cc = (c & 7) ^ (row & 7);
      gload16(Bt + (long)row * K + t * 64 + cc * 8, &sB[buf][c * 8]);
    }
  };

  f32x4 acc[16] = {};
  auto compute = [&](int buf) {
#pragma unroll
    for (int kx = 0; kx < 2; ++kx) {
      int ra = wm * 16 + lr;
      int ech = (kx * 32 + lk8) >> 3;
      bf16x8 af = *(const bf16x8*)((const char*)&sA[buf][0] +
                    (ra * 8 + (ech ^ (ra & 7))) * 16);
#pragma unroll
      for (int fn = 0; fn < 16; ++fn) {
        int rb = wn * 256 + fn * 16 + lr;
        bf16x8 bg = *(const bf16x8*)((const char*)&sB[buf][0] +
                      (rb * 8 + (ech ^ (rb & 7))) * 16);
        acc[fn] = __builtin_amdgcn_mfma_f32_16x16x32_bf16(af, bg, acc[fn], 0, 0, 0);
      }
    }
  };

  stage(0, 0);
  VMCNT(0); MEMFENCE;
  __syncthreads();
  if constexpr (DB) {
    for (int t = 0; t < NT; ++t) {
      if (t + 1 < NT) stage((t & 1) ^ 1, t + 1);
      compute(t & 1);
      VMCNT(0); MEMFENCE;
      __syncthreads();
    }
  } else {
    compute(0);
  }

  // ---- epilogue: bias + residual + row stats ----
  const int r0 = (lane >> 4) * 4;
  float s[4] = {}, s2[4] = {};
#pragma unroll
  for (int fn = 0; fn < 16; ++fn) {
    int gc = wn * 256 + fn * 16 + lr;
    float bv = bias[gc];
#pragma unroll
    for (int r = 0; r < 4; ++r) {
      long gr = bm0 + wm * 16 + r0 + r;
      float y = acc[fn][r] + bv + resid[gr * 512 + gc];
      acc[fn][r] = y;
      s[r] += y; s2[r] += y * y;
    }
  }
#pragma unroll
  for (int m = 1; m < 16; m <<= 1)
#pragma unroll
    for (int r = 0; r < 4; ++r) { s[r] += __shfl_xor(s[r], m); s2[r] += __shfl_xor(s2[r], m); }
  if (lr == 0) {
#pragma unroll
    for (int r = 0; r < 4; ++r) {
      lsum[wn][wm * 16 + r0 + r][0] = s[r];
      lsum[wn][wm * 16 + r0 + r][1] = s2[r];
    }
  }
  __syncthreads();
  float mean[4], rstd[4];
#pragma unroll
  for (int r = 0; r < 4; ++r) {
    int row = wm * 16 + r0 + r;
    float S1 = lsum[0][row][0] + lsum[1][row][0];
    float S2 = lsum[0][row][1] + lsum[1][row][1];
    mean[r] = S1 * (1.f / 512);
    float var = S2 * (1.f / 512) - mean[r] * mean[r];
    rstd[r] = rsqrtf(var + 1e-5f);
  }
#pragma unroll
  for (int fn = 0; fn < 16; ++fn) {
    int gc = wn * 256 + fn * 16 + lr;
    float gv = g[gc], bev = be[gc];
#pragma unroll
    for (int r = 0; r < 4; ++r) {
      long gr = bm0 + wm * 16 + r0 + r;
      float yn = (acc[fn][r] - mean[r]) * rstd[r] * gv + bev;
      fo[gr * 512 + gc] = yn;
      bo16[gr * 512 + gc] = (bf16)yn;
    }
  }
}

// ---------------------------------------------------------------------------
// Simple single-buffered MFMA GEMM; optional EXP fused into the epilogue.
// ---------------------------------------------------------------------------
template<int BM, int BN, int BK, int WM, int WN, typename OutT, bool EXPF>
__global__ __launch_bounds__(WM* WN * 64) void k_gemm(
    const bf16* __restrict__ A, const bf16* __restrict__ Bt, OutT* __restrict__ C,
    int K, int lda, int ldb, int ldc, float alpha, const float* __restrict__ bias,
    long aB, long bB, long cB)
{
  constexpr int NW = WM * WN;
  constexpr int T = NW * 64;
  constexpr int FM = BM / WM / 16;
  constexpr int FN = BN / WN / 16;
  constexpr int CPR = BK / 8;
  constexpr int CHA = BM * BK / 8;
  constexpr int CHB = BN * BK / 8;
  constexpr int IA = CHA / T;
  constexpr int IB = CHB / T;
  static_assert(CHA % T == 0 && CHB % T == 0, "staging divisibility");

  __shared__ bf16 sA[BM * BK];
  __shared__ bf16 sB[BN * BK];

  const int tid = threadIdx.x;
  const int lane = tid & 63;
  const int wid = tid >> 6;
  const int wm = wid / WN, wn = wid % WN;
  const int bm0 = blockIdx.x * BM;
  const int bn0 = blockIdx.y * BN;
  A += (long)blockIdx.z * aB + (long)bm0 * lda;
  Bt += (long)blockIdx.z * bB + (long)bn0 * ldb;
  C += (long)blockIdx.z * cB;

  f32x4 acc[FM][FN] = {};
  const int lr = lane & 15;
  const int lk = (lane >> 4) * 8;

  for (int k0 = 0; k0 < K; k0 += BK) {
#pragma unroll
    for (int i = 0; i < IA; ++i) {
      int c = i * T + tid;
      int row = c / CPR, kc = (c % CPR) * 8;
      gload16(A + (long)row * lda + k0 + kc, sA + c * 8);
    }
#pragma unroll
    for (int i = 0; i < IB; ++i) {
      int c = i * T + tid;
      int row = c / CPR, kc = (c % CPR) * 8;
      gload16(Bt + (long)row * ldb + k0 + kc, sB + c * 8);
    }
    asm volatile("s_waitcnt vmcnt(0)" ::: "memory");
    __syncthreads();

#pragma unroll
    for (int kk = 0; kk < BK; kk += 32) {
      bf16x8 af[FM], bg[FN];
#pragma unroll
      for (int m = 0; m < FM; ++m) {
        int row = wm * (FM * 16) + m * 16 + lr;
        af[m] = *(const bf16x8*)(sA + row * BK + kk + lk);
      }
#pragma unroll
      for (int n = 0; n < FN; ++n) {
        int col = wn * (FN * 16) + n * 16 + lr;
        bg[n] = *(const bf16x8*)(sB + col * BK + kk + lk);
      }
#pragma unroll
      for (int m = 0; m < FM; ++m)
#pragma unroll
        for (int n = 0; n < FN; ++n)
          acc[m][n] = __builtin_amdgcn_mfma_f32_16x16x32_bf16(af[m], bg[n], acc[m][n], 0, 0, 0);
    }
    __syncthreads();
  }

  const int r0 = (lane >> 4) * 4;
#pragma unroll
  for (int m = 0; m < FM; ++m) {
#pragma unroll
    for (int n = 0; n < FN; ++n) {
      int col = bn0 + wn * (FN * 16) + n * 16 + lr;
      float bv = bias ? bias[col] : 0.f;
#pragma unroll
      for (int r = 0; r < 4; ++r) {
        int row = bm0 + wm * (FM * 16) + m * 16 + r0 + r;
        float v = acc[m][n][r] * alpha + bv;
        if (EXPF) v = __expf(v);
        store_out(C + (long)row * ldc + col, v);
      }
    }
  }
}

// ---------------------------------------------------------------------------
__global__ __launch_bounds__(256) void k_cvt_dual(const float* __restrict__ in,
    float* __restrict__ fo, bf16* __restrict__ bo, long n4)
{
  long i = (long)blockIdx.x * 256 + threadIdx.x;
  if (i >= n4) return;
  float4 v = ((const float4*)in)[i];
  ((float4*)fo)[i] = v;
  bf16x4 h; h[0] = (bf16)v.x; h[1] = (bf16)v.y; h[2] = (bf16)v.z; h[3] = (bf16)v.w;
  ((bf16x4*)bo)[i] = h;
}

__global__ void k_tr(const float* __restrict__ in, bf16* __restrict__ out, int R, int C)
{
  __shared__ float t[32][33];
  int c0 = blockIdx.x * 32, r0 = blockIdx.y * 32;
#pragma unroll
  for (int i = 0; i < 4; ++i) {
    int r = r0 + threadIdx.y + i * 8;
    t[threadIdx.y + i * 8][threadIdx.x] = in[(long)r * C + c0 + threadIdx.x];
  }
  __syncthreads();
#pragma unroll
  for (int i = 0; i < 4; ++i) {
    int c = c0 + threadIdx.y + i * 8;
    out[(long)c * R + r0 + threadIdx.x] = (bf16)t[threadIdx.x][threadIdx.y + i * 8];
  }
}

__global__ __launch_bounds__(256) void k_woe(const float* __restrict__ wo, bf16* __restrict__ woet)
{
  int idx = blockIdx.x * 256 + threadIdx.x;
  int j = idx & 511, d = idx >> 9;
  float s = 0.f;
#pragma unroll
  for (int h = 0; h < 8; ++h) s += wo[(long)(h * 64 + d) * 512 + j];
  woet[(long)j * 64 + d] = (bf16)s;
}

__global__ void k_pack_bias(const float* __restrict__ bq, const float* __restrict__ bk,
                            const float* __restrict__ bv, float* __restrict__ o)
{
  int t = threadIdx.x;
  o[t] = bq[t]; o[64 + t] = bk[t]; o[128 + t] = bv[t];
}

__global__ __launch_bounds__(256) void k_colsum(const bf16* __restrict__ P, float* __restrict__ cs)
{
  int k = blockIdx.x * 256 + threadIdx.x;
  int b = blockIdx.y;
  const bf16* p = P + (long)b * S * S + k;
  float a0 = 0, a1 = 0, a2 = 0, a3 = 0;
  for (int q = 0; q < S; q += 4) {
    a0 += (float)p[(long)q * S];
    a1 += (float)p[(long)(q + 1) * S];
    a2 += (float)p[(long)(q + 2) * S];
    a3 += (float)p[(long)(q + 3) * S];
  }
  cs[b * S + k] = (a0 + a1) + (a2 + a3);
}

__global__ __launch_bounds__(256) void k_build_vnt(const bf16* __restrict__ qkv,
    const float* __restrict__ cs, bf16* __restrict__ vnt)
{
  int d = threadIdx.x & 63;
  int k = blockIdx.x * 4 + (threadIdx.x >> 6);
  int b = blockIdx.y;
  float v = (float)qkv[((long)(b * S + k)) * QKVLD + 128 + d];
  vnt[((long)b * HD + d) * S + k] = (bf16)(v / cs[b * S + k]);
}

// ---------------------------------------------------------------------------
extern "C" void kernel_launch(void* const* d_in, const int* in_sizes, int n_in,
                              void* d_out, int out_size, void* d_ws, size_t ws_size,
                              hipStream_t stream) {
  const float* x_in = (const float*)d_in[0];
  const float* wq = (const float*)d_in[1];
  const float* bq = (const float*)d_in[2];
  const float* wk = (const float*)d_in[3];
  const float* bk = (const float*)d_in[4];
  const float* wv = (const float*)d_in[5];
  const float* bv = (const float*)d_in[6];
  const float* wo = (const float*)d_in[7];
  const float* bo = (const float*)d_in[8];
  const float* ln_g = (const float*)d_in[9];
  const float* ln_b = (const float*)d_in[10];
  const float* w1 = (const float*)d_in[11];
  const float* b1 = (const float*)d_in[12];
  const float* w2 = (const float*)d_in[13];
  const float* b2 = (const float*)d_in[14];
  float* f_x = (float*)d_out;

  char* w = (char*)d_ws;
  size_t off = 0;
  auto alloc = [&](size_t bytes) { void* p = w + off; off += (bytes + 255) & ~(size_t)255; return p; };
  float* f_h   = (float*)alloc((size_t)BS * D * 4);
  bf16* b_x    = (bf16*)alloc((size_t)BS * D * 2);
  bf16* b_h    = (bf16*)alloc((size_t)BS * D * 2);
  bf16* b_qkv  = (bf16*)alloc((size_t)BS * QKVLD * 2);
  bf16* b_big  = (bf16*)alloc((size_t)BS * FF * 2);
  float* f_cs  = (float*)alloc((size_t)B * S * 4);
  bf16* b_vnt  = (bf16*)alloc((size_t)B * HD * S * 2);
  bf16* b_head = (bf16*)alloc((size_t)BS * HD * 2);
  bf16* wqkvT  = (bf16*)alloc((size_t)QKVLD * D * 2);
  bf16* woeT   = (bf16*)alloc((size_t)D * HD * 2);
  bf16* w1T    = (bf16*)alloc((size_t)FF * D * 2);
  bf16* w2T    = (bf16*)alloc((size_t)D * FF * 2);
  float* f_bqkv = (float*)alloc(192 * 4);

  // ---- setup ----
  k_cvt_dual<<<dim3(BS * D / 4 / 256), 256, 0, stream>>>(x_in, f_x, b_x, (long)BS * D / 4);
  k_tr<<<dim3(HD / 32, D / 32), dim3(32, 8), 0, stream>>>(wq, wqkvT, D, HD);
  k_tr<<<dim3(HD / 32, D / 32), dim3(32, 8), 0, stream>>>(wk, wqkvT + 64 * D, D, HD);
  k_tr<<<dim3(HD / 32, D / 32), dim3(32, 8), 0, stream>>>(wv, wqkvT + 128 * D, D, HD);
  k_tr<<<dim3(FF / 32, D / 32), dim3(32, 8), 0, stream>>>(w1, w1T, D, FF);
  k_tr<<<dim3(D / 32, FF / 32), dim3(32, 8), 0, stream>>>(w2, w2T, FF, D);
  k_woe<<<dim3(128), 256, 0, stream>>>(wo, woeT);
  k_pack_bias<<<1, 64, 0, stream>>>(bq, bk, bv, f_bqkv);

  for (int layer = 0; layer < 4; ++layer) {
    // fused QKV projection
    k_gemm<128, 64, 64, 4, 1, bf16, false><<<dim3(BS / 128, 3, 1), 256, 0, stream>>>(
        b_x, wqkvT, b_qkv, D, D, D, QKVLD, 1.f, f_bqkv, 0, 0, 0);
    // P = exp(Q K^T / 8) fused
    k_gemm<128, 128, 64, 2, 2, bf16, true><<<dim3(S / 128, S / 128, B), 256, 0, stream>>>(
        b_qkv, b_qkv + 64, b_big, HD, QKVLD, QKVLD, S, 0.125f, nullptr,
        (long)S * QKVLD, (long)S * QKVLD, (long)S * S);
    // colsum over q; fold 1/colsum into V^T
    k_colsum<<<dim3(S / 256, B), 256, 0, stream>>>(b_big, f_cs);
    k_build_vnt<<<dim3(S / 4, B), 256, 0, stream>>>(b_qkv, f_cs, b_vnt);
    // head = P @ Vn
    k_gemm<64, 64, 64, 4, 1, bf16, false><<<dim3(S / 64, 1, B), 256, 0, stream>>>(
        b_big, b_vnt, b_head, S, S, S, HD, 1.f, nullptr,
        (long)S * S, (long)HD * S, (long)S * HD);
    // h = LN(head @ wo_eff + bo + x)   [fused GEMM+LN, K=64]
    k_gemm_ln<1, false><<<dim3(BS / 64), 512, 0, stream>>>(
        b_head, woeT, f_x, bo, ln_g, ln_b, f_h, b_h);
    // ff1 = h @ w1 + b1   (8-phase 256x256)
    k_gemm8p<256, bf16><<<dim3((BS / 256) * (FF / 256)), 512, 0, stream>>>(
        b_h, w1T, b_big, D, D, D, FF, FF / 256, 1.f, b1);
    // x = LN(ff1 @ w2 + b2 + h)        [fused GEMM+LN, K=2048, double-buffered]
    k_gemm_ln<32, true><<<dim3(BS / 64), 512, 0, stream>>>(
        b_big, w2T, f_h, b2, ln_g, ln_b, f_x, b_x);
  }
}